// Round 4
// baseline (5136.744 us; speedup 1.0000x reference)
//
#include <hip/hip_runtime.h>
#include <hip/hip_bf16.h>

#define NE 800000
#define NN 50000
#define NG 16
#define ETOT (NE + NN)

typedef const unsigned short* w16p;
typedef unsigned short u16;

__device__ __forceinline__ float b2f(u16 u) {
  return __uint_as_float(((unsigned)u) << 16);
}
__device__ __forceinline__ u16 f2b(float f) {
  __hip_bfloat16 b = __float2bfloat16(f);
  return *(u16*)&b;
}
__device__ __forceinline__ void cv4(uint2 v, float* o) {
  o[0] = __uint_as_float(v.x << 16);
  o[1] = __uint_as_float(v.x & 0xFFFF0000u);
  o[2] = __uint_as_float(v.y << 16);
  o[3] = __uint_as_float(v.y & 0xFFFF0000u);
}
__device__ __forceinline__ void cv8(uint4 v, float* o) {
  o[0] = __uint_as_float(v.x << 16);
  o[1] = __uint_as_float(v.x & 0xFFFF0000u);
  o[2] = __uint_as_float(v.y << 16);
  o[3] = __uint_as_float(v.y & 0xFFFF0000u);
  o[4] = __uint_as_float(v.z << 16);
  o[5] = __uint_as_float(v.z & 0xFFFF0000u);
  o[6] = __uint_as_float(v.w << 16);
  o[7] = __uint_as_float(v.w & 0xFFFF0000u);
}
__device__ __forceinline__ unsigned pk2(float a, float b) {
  return (unsigned)f2b(a) | ((unsigned)f2b(b) << 16);
}
__device__ __forceinline__ unsigned f2key(float f) {
  unsigned u = __float_as_uint(f);
  return (u & 0x80000000u) ? ~u : (u | 0x80000000u);
}
__device__ __forceinline__ float key2f(unsigned k) {
  unsigned u = (k & 0x80000000u) ? (k ^ 0x80000000u) : ~k;
  return __uint_as_float(u);
}

// ================= dtype detector =================
// bf16-packed words: BOTH u16 halves have plausible bf16 exponent (or are zero).
// f32 words: low half = mantissa bits -> plausible only ~16% of the time.
__device__ __forceinline__ int plaus(unsigned h) {
  unsigned eh = (h >> 7) & 0xFF;
  return (h == 0) || (eh >= 100 && eh <= 140);
}
__global__ __launch_bounds__(256) void k_detect(const unsigned* __restrict__ a,
                                                const unsigned* __restrict__ b,
                                                const unsigned* __restrict__ c,
                                                int* __restrict__ flags) {
  __shared__ int cnt[3];
  if (threadIdx.x < 3) cnt[threadIdx.x] = 0;
  __syncthreads();
  const unsigned* arr[3] = {a, b, c};
  for (int k = 0; k < 3; k++) {
    int ok = 0;
    for (int i = threadIdx.x; i < 4096; i += 256) {
      unsigned w = arr[k][i];
      ok += (plaus(w & 0xFFFFu) && plaus(w >> 16)) ? 1 : 0;
    }
    atomicAdd(&cnt[k], ok);
  }
  __syncthreads();
  if (threadIdx.x == 0) {
    int f0 = cnt[0] > 2048, f1 = cnt[1] > 2048, f2 = cnt[2] > 2048;
    flags[0] = f0;            // x bf16?
    flags[1] = f1;            // weights bf16?
    flags[2] = f2;            // edge_attr bf16?
    flags[3] = f0 && f1 && f2; // output bf16 (JAX promotion)
  }
}

// ================= edge_attr column sums (self-loop mean row) =================
__global__ __launch_bounds__(256) void k_ea_colsum(const void* __restrict__ ea,
                                                   const int* __restrict__ flg,
                                                   float* __restrict__ sums) {
  bool eb = flg[2] != 0;
  int gt = blockIdx.x * 256 + threadIdx.x;
  int col = gt & 15;
  int row = gt >> 4;
  int rstride = (gridDim.x * 256) >> 4;
  float s = 0.f;
  if (eb) {
    const u16* p = (const u16*)ea;
    for (int e = row; e < NE; e += rstride) s += b2f(p[(size_t)e * 16 + col]);
  } else {
    const float* p = (const float*)ea;
    for (int e = row; e < NE; e += rstride) s += p[(size_t)e * 16 + col];
  }
  __shared__ float ls[256];
  ls[threadIdx.x] = s;
  __syncthreads();
  if (threadIdx.x < 16) {
    float t = 0.f;
    for (int i = threadIdx.x; i < 256; i += 16) t += ls[i];
    atomicAdd(&sums[threadIdx.x], t);
  }
}

// ==== fused 3x linear: out(bf16) = x @ W + b ====
// XMODE: 0 = x dtype from flg[0], 1 = x always bf16 (internal buffer)
template <int K, int N, int XMODE>
__global__ __launch_bounds__(256) void k_linear3(
    const void* __restrict__ xin, const int* __restrict__ flg,
    const void* W0, const void* W1, const void* W2,
    const void* b0, const void* b1, const void* b2,
    u16* __restrict__ o0, u16* __restrict__ o1, u16* __restrict__ o2, int M) {
  const void* W = blockIdx.y == 0 ? W0 : (blockIdx.y == 1 ? W1 : W2);
  const void* bb = blockIdx.y == 0 ? b0 : (blockIdx.y == 1 ? b1 : b2);
  u16* out = blockIdx.y == 0 ? o0 : (blockIdx.y == 1 ? o1 : o2);
  bool wb = flg[1] != 0;
  bool xb = (XMODE == 1) ? true : (flg[0] != 0);

  constexpr int TM = 32;
  constexpr int CPT = (N >= 64) ? 8 : 4;
  constexpr int TCOLS = N / CPT;  // 8
  __shared__ __align__(16) float Wf[K * N];
  __shared__ float xs[TM * (K + 1)];
  __shared__ float bfs[N];
  int tid = threadIdx.x;
  if (wb) {
    const u16* Wp = (const u16*)W;
    for (int i = tid; i < K * N / 8; i += 256) {
      float t[8];
      cv8(*(const uint4*)(Wp + i * 8), t);
#pragma unroll
      for (int q = 0; q < 8; q++) Wf[i * 8 + q] = t[q];
    }
  } else {
    const float* Wp = (const float*)W;
    for (int i = tid; i < K * N / 4; i += 256) {
      float4 v = *(const float4*)(Wp + i * 4);
      Wf[i * 4 + 0] = v.x; Wf[i * 4 + 1] = v.y;
      Wf[i * 4 + 2] = v.z; Wf[i * 4 + 3] = v.w;
    }
  }
  if (tid < N) bfs[tid] = wb ? b2f(((const u16*)bb)[tid]) : ((const float*)bb)[tid];
  int r0 = blockIdx.x * TM;
  if (xb) {
    const u16* xp = (const u16*)xin;
    for (int i = tid; i < TM * K / 8; i += 256) {
      int lr = i / (K / 8), lc = (i % (K / 8)) * 8;
      int gr = r0 + lr;
      float t[8] = {0, 0, 0, 0, 0, 0, 0, 0};
      if (gr < M) cv8(*(const uint4*)(xp + (size_t)gr * K + lc), t);
#pragma unroll
      for (int q = 0; q < 8; q++) xs[lr * (K + 1) + lc + q] = t[q];
    }
  } else {
    const float* xp = (const float*)xin;
    for (int i = tid; i < TM * K / 4; i += 256) {
      int lr = i / (K / 4), lc = (i % (K / 4)) * 4;
      int gr = r0 + lr;
      float4 v = {0, 0, 0, 0};
      if (gr < M) v = *(const float4*)(xp + (size_t)gr * K + lc);
      xs[lr * (K + 1) + lc + 0] = v.x;
      xs[lr * (K + 1) + lc + 1] = v.y;
      xs[lr * (K + 1) + lc + 2] = v.z;
      xs[lr * (K + 1) + lc + 3] = v.w;
    }
  }
  __syncthreads();
  int tc = tid % TCOLS, tr = tid / TCOLS;
  float acc[CPT];
#pragma unroll
  for (int c = 0; c < CPT; c++) acc[c] = bfs[tc * CPT + c];
#pragma unroll 4
  for (int k = 0; k < K; k++) {
    float xv = xs[tr * (K + 1) + k];
#pragma unroll
    for (int c = 0; c < CPT; c++) acc[c] += xv * Wf[k * N + tc * CPT + c];
  }
  int gr = r0 + tr;
  if (gr < M) {
    u16* op = out + (size_t)gr * N + tc * CPT;
    if constexpr (CPT == 8) {
      uint4 o;
      o.x = pk2(acc[0], acc[1]); o.y = pk2(acc[2], acc[3]);
      o.z = pk2(acc[4], acc[5]); o.w = pk2(acc[6], acc[7]);
      *(uint4*)op = o;
    } else {
      uint2 o;
      o.x = pk2(acc[0], acc[1]); o.y = pk2(acc[2], acc[3]);
      *(uint2*)op = o;
    }
  }
}

// ================= edge pass A: attention logits + segment max =================
template <int H, int C>
__global__ __launch_bounds__(256) void k_edgeA(
    const int* __restrict__ ei, const void* __restrict__ eattr,
    const int* __restrict__ flg, const float* __restrict__ mean_sums,
    const u16* __restrict__ xl, const u16* __restrict__ xr,
    const void* We, const void* att,
    u16* __restrict__ alpha, unsigned* __restrict__ amax) {
  constexpr int D = H * C;
  bool wb = flg[1] != 0;
  bool eb = flg[2] != 0;
  __shared__ __align__(16) float Wef[16 * D];
  __shared__ float attf[D];
  if (wb) {
    const u16* Wp = (const u16*)We;
    for (int i = threadIdx.x; i < 16 * D / 8; i += 256) {
      float t[8];
      cv8(*(const uint4*)(Wp + i * 8), t);
#pragma unroll
      for (int q = 0; q < 8; q++) Wef[i * 8 + q] = t[q];
    }
    for (int i = threadIdx.x; i < D; i += 256) attf[i] = b2f(((const u16*)att)[i]);
  } else {
    const float* Wp = (const float*)We;
    for (int i = threadIdx.x; i < 16 * D; i += 256) Wef[i] = Wp[i];
    for (int i = threadIdx.x; i < D; i += 256) attf[i] = ((const float*)att)[i];
  }
  __syncthreads();
  int e = blockIdx.x * 256 + threadIdx.x;
  if (e >= ETOT) return;
  int src, dst;
  float ea[16];
  if (e < NE) {
    src = ei[e];
    dst = ei[NE + e];
    if (eb) {
      const uint4* p = (const uint4*)((const u16*)eattr + (size_t)e * 16);
      cv8(p[0], ea);
      cv8(p[1], ea + 8);
    } else {
      const float4* p = (const float4*)((const float*)eattr + (size_t)e * 16);
#pragma unroll
      for (int q = 0; q < 4; q++) {
        float4 v = p[q];
        ea[q * 4 + 0] = v.x; ea[q * 4 + 1] = v.y;
        ea[q * 4 + 2] = v.z; ea[q * 4 + 3] = v.w;
      }
    }
  } else {
    src = dst = e - NE;
#pragma unroll
    for (int k = 0; k < 16; k++) ea[k] = mean_sums[k] * (1.0f / NE);
  }
  const uint2* xlp = (const uint2*)(xl + (size_t)src * D);
  const uint2* xrp = (const uint2*)(xr + (size_t)dst * D);
  const float4* Wef4 = (const float4*)Wef;
  float al[H];
#pragma unroll
  for (int h = 0; h < H; h++) al[h] = 0.f;
#pragma unroll
  for (int j4 = 0; j4 < D / 4; j4++) {
    float xls[4], xrs[4];
    cv4(xlp[j4], xls);
    cv4(xrp[j4], xrs);
    float ev[4] = {0.f, 0.f, 0.f, 0.f};
#pragma unroll
    for (int k = 0; k < 16; k++) {
      float a = ea[k];
      float4 w = Wef4[k * (D / 4) + j4];
      ev[0] += a * w.x; ev[1] += a * w.y; ev[2] += a * w.z; ev[3] += a * w.w;
    }
#pragma unroll
    for (int q = 0; q < 4; q++) {
      int j = j4 * 4 + q;
      float m = xls[q] + xrs[q] + ev[q];
      m = (m > 0.f) ? m : 0.2f * m;
      al[j / C] += m * attf[j];
    }
  }
#pragma unroll
  for (int h = 0; h < H; h++) {
    alpha[(size_t)e * H + h] = f2b(al[h]);
    atomicMax(&amax[dst * H + h], f2key(al[h]));
  }
}

// ================= edge pass B: exp + segment denom =================
template <int H>
__global__ __launch_bounds__(256) void k_edgeB(const int* __restrict__ ei,
                                               u16* __restrict__ alpha,
                                               const unsigned* __restrict__ amax,
                                               float* __restrict__ denom) {
  int e = blockIdx.x * 256 + threadIdx.x;
  if (e >= ETOT) return;
  int dst = (e < NE) ? ei[NE + e] : e - NE;
#pragma unroll
  for (int h = 0; h < H; h++) {
    float mx = key2f(amax[dst * H + h]);
    float ex = __expf(b2f(alpha[(size_t)e * H + h]) - mx);
    alpha[(size_t)e * H + h] = f2b(ex);
    atomicAdd(&denom[dst * H + h], ex);
  }
}

// ================= edge pass C: weighted scatter-add =================
template <int H, int C>
__global__ __launch_bounds__(256) void k_edgeC(const int* __restrict__ ei,
                                               const u16* __restrict__ alpha,
                                               const float* __restrict__ denom,
                                               const u16* __restrict__ xl,
                                               float* __restrict__ agg) {
  constexpr int D = H * C;
  int e = blockIdx.x * 256 + threadIdx.x;
  if (e >= ETOT) return;
  int src, dst;
  if (e < NE) { src = ei[e]; dst = ei[NE + e]; } else { src = dst = e - NE; }
  float w[H];
#pragma unroll
  for (int h = 0; h < H; h++)
    w[h] = b2f(alpha[(size_t)e * H + h]) / (denom[dst * H + h] + 1e-16f);
  const uint2* xlp = (const uint2*)(xl + (size_t)src * D);
  float* ag = agg + (size_t)dst * D;
#pragma unroll
  for (int j4 = 0; j4 < D / 4; j4++) {
    float v[4];
    cv4(xlp[j4], v);
    float ww = w[(j4 * 4) / C];
    atomicAdd(&ag[j4 * 4 + 0], v[0] * ww);
    atomicAdd(&ag[j4 * 4 + 1], v[1] * ww);
    atomicAdd(&ag[j4 * 4 + 2], v[2] * ww);
    atomicAdd(&ag[j4 * 4 + 3], v[3] * ww);
  }
}

// ================= batch-norm reduce =================
template <int D>
__global__ __launch_bounds__(256) void k_bnred(const float* __restrict__ v,
                                               float* __restrict__ sum,
                                               float* __restrict__ sq, int M) {
  constexpr int RB = 256 / D;
  int tid = threadIdx.x;
  int c = tid % D;
  int rg = tid / D;
  float s = 0.f, q = 0.f;
  for (int r = blockIdx.x * RB + rg; r < M; r += gridDim.x * RB) {
    float x = v[(size_t)r * D + c];
    s += x;
    q += x * x;
  }
  __shared__ float ls[256], lq[256];
  ls[tid] = s; lq[tid] = q;
  __syncthreads();
  if (tid < D) {
    float ts = 0.f, tq = 0.f;
    for (int i = tid; i < 256; i += D) { ts += ls[i]; tq += lq[i]; }
    atomicAdd(&sum[tid], ts);
    atomicAdd(&sq[tid], tq);
  }
}

// ================= batch-norm apply + skip + ELU =================
template <int D>
__global__ __launch_bounds__(256) void k_bnapply(const float* __restrict__ agg,
                                                 const u16* __restrict__ hp,
                                                 const float* __restrict__ sum,
                                                 const float* __restrict__ sq,
                                                 const void* g, const void* b,
                                                 const int* __restrict__ flg,
                                                 u16* __restrict__ out, int M) {
  bool wb = flg[1] != 0;
  int idx = blockIdx.x * 256 + threadIdx.x;
  if (idx >= M * D) return;
  int c = idx & (D - 1);
  float gc = wb ? b2f(((const u16*)g)[c]) : ((const float*)g)[c];
  float bc = wb ? b2f(((const u16*)b)[c]) : ((const float*)b)[c];
  float mu = sum[c] * (1.f / M);
  float var = fmaxf(sq[c] * (1.f / M) - mu * mu, 0.f);
  float sc = rsqrtf(var + 1e-5f) * gc;
  float v = (agg[idx] - mu) * sc + bc + b2f(hp[idx]);
  v = v > 0.f ? v : expm1f(v);
  out[idx] = f2b(v);
}

// ================= graph pooling =================
__global__ __launch_bounds__(256) void k_pool(const u16* __restrict__ h2,
                                              const int* __restrict__ batch,
                                              float* __restrict__ pool_sum,
                                              unsigned* __restrict__ pool_maxk,
                                              float* __restrict__ pool_cnt, int M) {
  const int NPB = 2048;
  int c = threadIdx.x & 31;
  int rg = threadIdx.x >> 5;
  int n0 = blockIdx.x * NPB;
  int nend = min(n0 + NPB, M);
  int cur = -1;
  float s = 0.f, mx = 0.f;
  int cnt = 0;
  for (int n = n0 + rg; n < nend; n += 8) {
    int g = batch[n];
    float v = b2f(h2[(size_t)n * 32 + c]);
    if (g != cur) {
      if (cur >= 0) {
        atomicAdd(&pool_sum[cur * 32 + c], s);
        atomicMax(&pool_maxk[cur * 32 + c], f2key(mx));
        if (c == 0) atomicAdd(&pool_cnt[cur], (float)cnt);
      }
      cur = g; s = 0.f; mx = -INFINITY; cnt = 0;
    }
    s += v;
    mx = fmaxf(mx, v);
    cnt++;
  }
  if (cur >= 0) {
    atomicAdd(&pool_sum[cur * 32 + c], s);
    atomicMax(&pool_maxk[cur * 32 + c], f2key(mx));
    if (c == 0) atomicAdd(&pool_cnt[cur], (float)cnt);
  }
}

__global__ __launch_bounds__(256) void k_poolfinal(const float* __restrict__ pool_sum,
                                                   const unsigned* __restrict__ pool_maxk,
                                                   const float* __restrict__ pool_cnt,
                                                   const int* __restrict__ flg,
                                                   void* __restrict__ out) {
  bool ob = flg[3] != 0;
  int idx = blockIdx.x * 256 + threadIdx.x;
  if (idx >= NG * 64) return;
  int g = idx / 64, c = idx % 64;
  float cnt = pool_cnt[g];
  float val;
  if (c < 32) val = pool_sum[g * 32 + c] / fmaxf(cnt, 1.f);
  else val = cnt > 0.f ? key2f(pool_maxk[g * 32 + (c - 32)]) : 0.f;
  if (ob) ((u16*)out)[idx] = f2b(val);
  else ((float*)out)[idx] = val;
}

extern "C" void kernel_launch(void* const* d_in, const int* in_sizes, int n_in,
                              void* d_out, int out_size, void* d_ws, size_t ws_size,
                              hipStream_t stream) {
  (void)in_sizes; (void)n_in; (void)out_size; (void)ws_size;
  const void* x     = d_in[0];
  const int*  ei    = (const int*)d_in[1];
  const void* eattr = d_in[2];
  const int*  batch = (const int*)d_in[3];
  const void* skip1_W = d_in[4];
  const void* skip1_b = d_in[5];
  const void* c1_Wl = d_in[6];
  const void* c1_bl = d_in[7];
  const void* c1_Wr = d_in[8];
  const void* c1_br = d_in[9];
  const void* c1_We = d_in[10];
  const void* c1_att = d_in[11];
  // d_in[12] conv1_bias: cancelled exactly by BN mean-subtraction
  const void* bn1_g = d_in[13];
  const void* bn1_b = d_in[14];
  const void* skip2_W = d_in[15];
  const void* skip2_b = d_in[16];
  const void* c2_Wl = d_in[17];
  const void* c2_bl = d_in[18];
  const void* c2_Wr = d_in[19];
  const void* c2_br = d_in[20];
  const void* c2_We = d_in[21];
  const void* c2_att = d_in[22];
  // d_in[23] conv2_bias: cancelled by BN
  const void* bn2_g = d_in[24];
  const void* bn2_b = d_in[25];

  float* ws = (float*)d_ws;
  size_t off = 0;
  auto alloc = [&](size_t nfl) {
    float* p = ws + off;
    off += (nfl + 15) & ~(size_t)15;
    return p;
  };
  // ---- zero-initialized accumulator region (memset #1) ----
  int*   flags      = (int*)alloc(16);
  float* mean_sums  = alloc(16);
  unsigned* amax1   = (unsigned*)alloc((size_t)NN * 2);
  float* denom1     = alloc((size_t)NN * 2);
  float* aggA       = alloc((size_t)NN * 64);  // agg1; first NN*32 re-zeroed as agg2
  float* bnsum1     = alloc(64);
  float* bnsq1      = alloc(64);
  unsigned* amax2   = (unsigned*)alloc(NN);
  float* denom2     = alloc(NN);
  float* bnsum2     = alloc(32);
  float* bnsq2      = alloc(32);
  float* pool_cnt   = alloc(NG);
  float* pool_sum   = alloc(NG * 32);
  unsigned* pool_maxk = (unsigned*)alloc(NG * 32);
  size_t zbytes = off * sizeof(float);
  // ---- bf16 scratch (sizes in float units; fully overwritten before read) ----
  u16* xl1 = (u16*)alloc((size_t)NN * 32);  // NN*64 bf16
  u16* xr1 = (u16*)alloc((size_t)NN * 32);  // NN*64 bf16; h1 reuses
  u16* hp1 = (u16*)alloc((size_t)NN * 32);  // NN*64 bf16; hp2/h2 reuse halves
  u16* alpha1 = (u16*)alloc((size_t)ETOT);  // ETOT*2 bf16
  float* agg1 = aggA;
  float* agg2 = aggA;
  // layer-2 overlays (source regions dead by then)
  u16* h1  = xr1;
  u16* xl2 = xl1;
  u16* xr2 = xl1 + (size_t)NN * 32;
  u16* hp2 = hp1;
  u16* h2  = hp1 + (size_t)NN * 32;
  u16* alpha2 = alpha1;

  hipMemsetAsync(d_ws, 0, zbytes, stream);
  k_detect<<<1, 256, 0, stream>>>((const unsigned*)x, (const unsigned*)skip1_W,
                                  (const unsigned*)eattr, flags);
  k_ea_colsum<<<128, 256, 0, stream>>>(eattr, flags, mean_sums);

  {
    dim3 g((NN + 31) / 32, 3);
    k_linear3<128, 64, 0><<<g, 256, 0, stream>>>(x, flags, c1_Wl, c1_Wr, skip1_W,
                                                 c1_bl, c1_br, skip1_b,
                                                 xl1, xr1, hp1, NN);
  }
  int eg = (ETOT + 255) / 256;
  k_edgeA<2, 32><<<eg, 256, 0, stream>>>(ei, eattr, flags, mean_sums, xl1, xr1,
                                         c1_We, c1_att, alpha1, amax1);
  k_edgeB<2><<<eg, 256, 0, stream>>>(ei, alpha1, amax1, denom1);
  k_edgeC<2, 32><<<eg, 256, 0, stream>>>(ei, alpha1, denom1, xl1, agg1);
  k_bnred<64><<<256, 256, 0, stream>>>(agg1, bnsum1, bnsq1, NN);
  k_bnapply<64><<<(NN * 64 + 255) / 256, 256, 0, stream>>>(agg1, hp1, bnsum1, bnsq1,
                                                           bn1_g, bn1_b, flags, h1, NN);

  hipMemsetAsync(agg2, 0, (size_t)NN * 32 * sizeof(float), stream);
  {
    dim3 g((NN + 31) / 32, 3);
    k_linear3<64, 32, 1><<<g, 256, 0, stream>>>(h1, flags, c2_Wl, c2_Wr, skip2_W,
                                                c2_bl, c2_br, skip2_b,
                                                xl2, xr2, hp2, NN);
  }
  k_edgeA<1, 32><<<eg, 256, 0, stream>>>(ei, eattr, flags, mean_sums, xl2, xr2,
                                         c2_We, c2_att, alpha2, amax2);
  k_edgeB<1><<<eg, 256, 0, stream>>>(ei, alpha2, amax2, denom2);
  k_edgeC<1, 32><<<eg, 256, 0, stream>>>(ei, alpha2, denom2, xl2, agg2);
  k_bnred<32><<<256, 256, 0, stream>>>(agg2, bnsum2, bnsq2, NN);
  k_bnapply<32><<<(NN * 32 + 255) / 256, 256, 0, stream>>>(agg2, hp2, bnsum2, bnsq2,
                                                           bn2_g, bn2_b, flags, h2, NN);

  k_pool<<<(NN + 2047) / 2048, 256, 0, stream>>>(h2, batch, pool_sum, pool_maxk, pool_cnt, NN);
  k_poolfinal<<<4, 256, 0, stream>>>(pool_sum, pool_maxk, pool_cnt, flags, d_out);
}

// Round 5
// 936.490 us; speedup vs baseline: 5.4851x; 5.4851x over previous
//
#include <hip/hip_runtime.h>
#include <hip/hip_bf16.h>

#define NE 800000
#define NN 50000
#define NG 16
#define ETOT (NE + NN)

typedef unsigned short u16;

__device__ __forceinline__ float b2f(u16 u) {
  return __uint_as_float(((unsigned)u) << 16);
}
__device__ __forceinline__ u16 f2b(float f) {
  __hip_bfloat16 b = __float2bfloat16(f);
  return *(u16*)&b;
}
__device__ __forceinline__ void cv4(uint2 v, float* o) {
  o[0] = __uint_as_float(v.x << 16);
  o[1] = __uint_as_float(v.x & 0xFFFF0000u);
  o[2] = __uint_as_float(v.y << 16);
  o[3] = __uint_as_float(v.y & 0xFFFF0000u);
}
__device__ __forceinline__ void cv8(uint4 v, float* o) {
  o[0] = __uint_as_float(v.x << 16);
  o[1] = __uint_as_float(v.x & 0xFFFF0000u);
  o[2] = __uint_as_float(v.y << 16);
  o[3] = __uint_as_float(v.y & 0xFFFF0000u);
  o[4] = __uint_as_float(v.z << 16);
  o[5] = __uint_as_float(v.z & 0xFFFF0000u);
  o[6] = __uint_as_float(v.w << 16);
  o[7] = __uint_as_float(v.w & 0xFFFF0000u);
}
__device__ __forceinline__ unsigned pk2(float a, float b) {
  return (unsigned)f2b(a) | ((unsigned)f2b(b) << 16);
}
__device__ __forceinline__ unsigned f2key(float f) {
  unsigned u = __float_as_uint(f);
  return (u & 0x80000000u) ? ~u : (u | 0x80000000u);
}
__device__ __forceinline__ float key2f(unsigned k) {
  unsigned u = (k & 0x80000000u) ? (k ^ 0x80000000u) : ~k;
  return __uint_as_float(u);
}

// ================= dtype detector (kept from R4 — proven) =================
__device__ __forceinline__ int plaus(unsigned h) {
  unsigned eh = (h >> 7) & 0xFF;
  return (h == 0) || (eh >= 100 && eh <= 140);
}
__global__ __launch_bounds__(256) void k_detect(const unsigned* __restrict__ a,
                                                const unsigned* __restrict__ b,
                                                const unsigned* __restrict__ c,
                                                int* __restrict__ flags) {
  __shared__ int cnt[3];
  if (threadIdx.x < 3) cnt[threadIdx.x] = 0;
  __syncthreads();
  const unsigned* arr[3] = {a, b, c};
  for (int k = 0; k < 3; k++) {
    int ok = 0;
    for (int i = threadIdx.x; i < 4096; i += 256) {
      unsigned w = arr[k][i];
      ok += (plaus(w & 0xFFFFu) && plaus(w >> 16)) ? 1 : 0;
    }
    atomicAdd(&cnt[k], ok);
  }
  __syncthreads();
  if (threadIdx.x == 0) {
    int f0 = cnt[0] > 2048, f1 = cnt[1] > 2048, f2 = cnt[2] > 2048;
    flags[0] = f0;
    flags[1] = f1;
    flags[2] = f2;
    flags[3] = f0 && f1 && f2;
  }
}

// ================= edge_attr column sums (self-loop mean row) =================
__global__ __launch_bounds__(256) void k_ea_colsum(const void* __restrict__ ea,
                                                   const int* __restrict__ flg,
                                                   float* __restrict__ sums) {
  bool eb = flg[2] != 0;
  int gt = blockIdx.x * 256 + threadIdx.x;
  int col = gt & 15;
  int row = gt >> 4;
  int rstride = (gridDim.x * 256) >> 4;
  float s = 0.f;
  if (eb) {
    const u16* p = (const u16*)ea;
    for (int e = row; e < NE; e += rstride) s += b2f(p[(size_t)e * 16 + col]);
  } else {
    const float* p = (const float*)ea;
    for (int e = row; e < NE; e += rstride) s += p[(size_t)e * 16 + col];
  }
  __shared__ float ls[256];
  ls[threadIdx.x] = s;
  __syncthreads();
  if (threadIdx.x < 16) {
    float t = 0.f;
    for (int i = threadIdx.x; i < 256; i += 16) t += ls[i];
    atomicAdd(&sums[threadIdx.x], t);
  }
}

// ================= CSR build: histogram + scan + cursor copy =================
__global__ __launch_bounds__(256) void k_hist(const int* __restrict__ ei,
                                              int* __restrict__ deg) {
  int e = blockIdx.x * 256 + threadIdx.x;
  if (e >= ETOT) return;
  int dst = (e < NE) ? ei[NE + e] : e - NE;
  atomicAdd(&deg[dst], 1);
}

__global__ __launch_bounds__(256) void k_scan(const int* __restrict__ deg,
                                              int* __restrict__ start) {
  __shared__ int ps[256];
  int t = threadIdx.x;
  const int CH = (NN + 255) / 256;
  int b0 = t * CH;
  int bend = min(b0 + CH, NN);
  int s = 0;
  for (int i = b0; i < bend; i++) s += deg[i];
  ps[t] = s;
  __syncthreads();
  for (int ofs = 1; ofs < 256; ofs <<= 1) {
    int v = (t >= ofs) ? ps[t - ofs] : 0;
    __syncthreads();
    ps[t] += v;
    __syncthreads();
  }
  int run = (t == 0) ? 0 : ps[t - 1];
  for (int i = b0; i < bend; i++) {
    start[i] = run;
    run += deg[i];
  }
  if (t == 255) start[NN] = run;
}

__global__ __launch_bounds__(256) void k_copy(const int* __restrict__ a,
                                              int* __restrict__ b, int n) {
  int i = blockIdx.x * 256 + threadIdx.x;
  if (i < n) b[i] = a[i];
}

// ==== fused 3x linear: out(bf16) = x @ W + b (proven in R4) ====
template <int K, int N, int XMODE>
__global__ __launch_bounds__(256) void k_linear3(
    const void* __restrict__ xin, const int* __restrict__ flg,
    const void* W0, const void* W1, const void* W2,
    const void* b0, const void* b1, const void* b2,
    u16* __restrict__ o0, u16* __restrict__ o1, u16* __restrict__ o2, int M) {
  const void* W = blockIdx.y == 0 ? W0 : (blockIdx.y == 1 ? W1 : W2);
  const void* bb = blockIdx.y == 0 ? b0 : (blockIdx.y == 1 ? b1 : b2);
  u16* out = blockIdx.y == 0 ? o0 : (blockIdx.y == 1 ? o1 : o2);
  bool wb = flg[1] != 0;
  bool xb = (XMODE == 1) ? true : (flg[0] != 0);

  constexpr int TM = 32;
  constexpr int CPT = (N >= 64) ? 8 : 4;
  constexpr int TCOLS = N / CPT;
  __shared__ __align__(16) float Wf[K * N];
  __shared__ float xs[TM * (K + 1)];
  __shared__ float bfs[N];
  int tid = threadIdx.x;
  if (wb) {
    const u16* Wp = (const u16*)W;
    for (int i = tid; i < K * N / 8; i += 256) {
      float t[8];
      cv8(*(const uint4*)(Wp + i * 8), t);
#pragma unroll
      for (int q = 0; q < 8; q++) Wf[i * 8 + q] = t[q];
    }
  } else {
    const float* Wp = (const float*)W;
    for (int i = tid; i < K * N / 4; i += 256) {
      float4 v = *(const float4*)(Wp + i * 4);
      Wf[i * 4 + 0] = v.x; Wf[i * 4 + 1] = v.y;
      Wf[i * 4 + 2] = v.z; Wf[i * 4 + 3] = v.w;
    }
  }
  if (tid < N) bfs[tid] = wb ? b2f(((const u16*)bb)[tid]) : ((const float*)bb)[tid];
  int r0 = blockIdx.x * TM;
  if (xb) {
    const u16* xp = (const u16*)xin;
    for (int i = tid; i < TM * K / 8; i += 256) {
      int lr = i / (K / 8), lc = (i % (K / 8)) * 8;
      int gr = r0 + lr;
      float t[8] = {0, 0, 0, 0, 0, 0, 0, 0};
      if (gr < M) cv8(*(const uint4*)(xp + (size_t)gr * K + lc), t);
#pragma unroll
      for (int q = 0; q < 8; q++) xs[lr * (K + 1) + lc + q] = t[q];
    }
  } else {
    const float* xp = (const float*)xin;
    for (int i = tid; i < TM * K / 4; i += 256) {
      int lr = i / (K / 4), lc = (i % (K / 4)) * 4;
      int gr = r0 + lr;
      float4 v = {0, 0, 0, 0};
      if (gr < M) v = *(const float4*)(xp + (size_t)gr * K + lc);
      xs[lr * (K + 1) + lc + 0] = v.x;
      xs[lr * (K + 1) + lc + 1] = v.y;
      xs[lr * (K + 1) + lc + 2] = v.z;
      xs[lr * (K + 1) + lc + 3] = v.w;
    }
  }
  __syncthreads();
  int tc = tid % TCOLS, tr = tid / TCOLS;
  float acc[CPT];
#pragma unroll
  for (int c = 0; c < CPT; c++) acc[c] = bfs[tc * CPT + c];
#pragma unroll 4
  for (int k = 0; k < K; k++) {
    float xv = xs[tr * (K + 1) + k];
#pragma unroll
    for (int c = 0; c < CPT; c++) acc[c] += xv * Wf[k * N + tc * CPT + c];
  }
  int gr = r0 + tr;
  if (gr < M) {
    u16* op = out + (size_t)gr * N + tc * CPT;
    if constexpr (CPT == 8) {
      uint4 o;
      o.x = pk2(acc[0], acc[1]); o.y = pk2(acc[2], acc[3]);
      o.z = pk2(acc[4], acc[5]); o.w = pk2(acc[6], acc[7]);
      *(uint4*)op = o;
    } else {
      uint2 o;
      o.x = pk2(acc[0], acc[1]); o.y = pk2(acc[2], acc[3]);
      *(uint2*)op = o;
    }
  }
}

// ===== edge pass A: attention logits -> CSR slot (src:u16, logits:bf16) =====
template <int H, int C>
__global__ __launch_bounds__(256) void k_edgeA(
    const int* __restrict__ ei, const void* __restrict__ eattr,
    const int* __restrict__ flg, const float* __restrict__ mean_sums,
    const u16* __restrict__ xl, const u16* __restrict__ xr,
    const void* We, const void* att,
    int* __restrict__ cursor, u16* __restrict__ csr_src,
    void* __restrict__ csr_lg) {
  constexpr int D = H * C;
  bool wb = flg[1] != 0;
  bool eb = flg[2] != 0;
  __shared__ __align__(16) float Wef[16 * D];
  __shared__ float attf[D];
  if (wb) {
    const u16* Wp = (const u16*)We;
    for (int i = threadIdx.x; i < 16 * D / 8; i += 256) {
      float t[8];
      cv8(*(const uint4*)(Wp + i * 8), t);
#pragma unroll
      for (int q = 0; q < 8; q++) Wef[i * 8 + q] = t[q];
    }
    for (int i = threadIdx.x; i < D; i += 256) attf[i] = b2f(((const u16*)att)[i]);
  } else {
    const float* Wp = (const float*)We;
    for (int i = threadIdx.x; i < 16 * D; i += 256) Wef[i] = Wp[i];
    for (int i = threadIdx.x; i < D; i += 256) attf[i] = ((const float*)att)[i];
  }
  __syncthreads();
  int e = blockIdx.x * 256 + threadIdx.x;
  if (e >= ETOT) return;
  int src, dst;
  float ea[16];
  if (e < NE) {
    src = ei[e];
    dst = ei[NE + e];
    if (eb) {
      const uint4* p = (const uint4*)((const u16*)eattr + (size_t)e * 16);
      cv8(p[0], ea);
      cv8(p[1], ea + 8);
    } else {
      const float4* p = (const float4*)((const float*)eattr + (size_t)e * 16);
#pragma unroll
      for (int q = 0; q < 4; q++) {
        float4 v = p[q];
        ea[q * 4 + 0] = v.x; ea[q * 4 + 1] = v.y;
        ea[q * 4 + 2] = v.z; ea[q * 4 + 3] = v.w;
      }
    }
  } else {
    src = dst = e - NE;
#pragma unroll
    for (int k = 0; k < 16; k++) ea[k] = mean_sums[k] * (1.0f / NE);
  }
  const uint2* xlp = (const uint2*)(xl + (size_t)src * D);
  const uint2* xrp = (const uint2*)(xr + (size_t)dst * D);
  const float4* Wef4 = (const float4*)Wef;
  float al[H];
#pragma unroll
  for (int h = 0; h < H; h++) al[h] = 0.f;
#pragma unroll
  for (int j4 = 0; j4 < D / 4; j4++) {
    float xls[4], xrs[4];
    cv4(xlp[j4], xls);
    cv4(xrp[j4], xrs);
    float ev[4] = {0.f, 0.f, 0.f, 0.f};
#pragma unroll
    for (int k = 0; k < 16; k++) {
      float a = ea[k];
      float4 w = Wef4[k * (D / 4) + j4];
      ev[0] += a * w.x; ev[1] += a * w.y; ev[2] += a * w.z; ev[3] += a * w.w;
    }
#pragma unroll
    for (int q = 0; q < 4; q++) {
      int j = j4 * 4 + q;
      float m = xls[q] + xrs[q] + ev[q];
      m = (m > 0.f) ? m : 0.2f * m;
      al[j / C] += m * attf[j];
    }
  }
  int pos = atomicAdd(&cursor[dst], 1);
  csr_src[pos] = (u16)src;
  if constexpr (H == 2) {
    ((unsigned*)csr_lg)[pos] = pk2(al[0], al[1]);
  } else {
    ((u16*)csr_lg)[pos] = f2b(al[0]);
  }
}

// ===== gather-reduce: one wave-subgroup per dst node, online softmax =====
template <int H, int C>
__global__ __launch_bounds__(256) void k_reduce(
    const int* __restrict__ start, const u16* __restrict__ csr_src,
    const void* __restrict__ csr_lg, const u16* __restrict__ xl,
    u16* __restrict__ agg) {
  constexpr int D = H * C;
  constexpr int NPW = 64 / D;  // nodes per wave
  int wid = (blockIdx.x * 256 + threadIdx.x) >> 6;
  int lane = threadIdx.x & 63;
  int node = wid * NPW + lane / D;
  if (node >= NN) return;
  int ch = lane % D;
  int h = ch / C;
  int s0 = start[node], s1 = start[node + 1];
  float m = -INFINITY, ssum = 0.f, acc = 0.f;
  for (int p = s0; p < s1; p++) {
    int src = csr_src[p];
    float lg;
    if constexpr (H == 2) {
      unsigned w = ((const unsigned*)csr_lg)[p];
      lg = b2f((u16)(h == 0 ? (w & 0xFFFFu) : (w >> 16)));
    } else {
      lg = b2f(((const u16*)csr_lg)[p]);
    }
    float xv = b2f(xl[(size_t)src * D + ch]);
    float nm = fmaxf(m, lg);
    float sc = __expf(m - nm);   // first iter: exp(-inf) = 0
    float w2 = __expf(lg - nm);
    ssum = ssum * sc + w2;
    acc = acc * sc + w2 * xv;
    m = nm;
  }
  agg[(size_t)node * D + ch] = f2b(acc / (ssum + 1e-16f));
}

// ================= batch-norm reduce (agg bf16) =================
template <int D>
__global__ __launch_bounds__(256) void k_bnred(const u16* __restrict__ v,
                                               float* __restrict__ sum,
                                               float* __restrict__ sq, int M) {
  constexpr int RB = 256 / D;
  int tid = threadIdx.x;
  int c = tid % D;
  int rg = tid / D;
  float s = 0.f, q = 0.f;
  for (int r = blockIdx.x * RB + rg; r < M; r += gridDim.x * RB) {
    float x = b2f(v[(size_t)r * D + c]);
    s += x;
    q += x * x;
  }
  __shared__ float ls[256], lq[256];
  ls[tid] = s; lq[tid] = q;
  __syncthreads();
  if (tid < D) {
    float ts = 0.f, tq = 0.f;
    for (int i = tid; i < 256; i += D) { ts += ls[i]; tq += lq[i]; }
    atomicAdd(&sum[tid], ts);
    atomicAdd(&sq[tid], tq);
  }
}

// ================= batch-norm apply + skip + ELU =================
template <int D>
__global__ __launch_bounds__(256) void k_bnapply(const u16* __restrict__ agg,
                                                 const u16* __restrict__ hp,
                                                 const float* __restrict__ sum,
                                                 const float* __restrict__ sq,
                                                 const void* g, const void* b,
                                                 const int* __restrict__ flg,
                                                 u16* __restrict__ out, int M) {
  bool wb = flg[1] != 0;
  int idx = blockIdx.x * 256 + threadIdx.x;
  if (idx >= M * D) return;
  int c = idx & (D - 1);
  float gc = wb ? b2f(((const u16*)g)[c]) : ((const float*)g)[c];
  float bc = wb ? b2f(((const u16*)b)[c]) : ((const float*)b)[c];
  float mu = sum[c] * (1.f / M);
  float var = fmaxf(sq[c] * (1.f / M) - mu * mu, 0.f);
  float sc = rsqrtf(var + 1e-5f) * gc;
  float v = (b2f(agg[idx]) - mu) * sc + bc + b2f(hp[idx]);
  v = v > 0.f ? v : expm1f(v);
  out[idx] = f2b(v);
}

// ================= graph pooling =================
__global__ __launch_bounds__(256) void k_pool(const u16* __restrict__ h2,
                                              const int* __restrict__ batch,
                                              float* __restrict__ pool_sum,
                                              unsigned* __restrict__ pool_maxk,
                                              float* __restrict__ pool_cnt, int M) {
  const int NPB = 2048;
  int c = threadIdx.x & 31;
  int rg = threadIdx.x >> 5;
  int n0 = blockIdx.x * NPB;
  int nend = min(n0 + NPB, M);
  int cur = -1;
  float s = 0.f, mx = 0.f;
  int cnt = 0;
  for (int n = n0 + rg; n < nend; n += 8) {
    int g = batch[n];
    float v = b2f(h2[(size_t)n * 32 + c]);
    if (g != cur) {
      if (cur >= 0) {
        atomicAdd(&pool_sum[cur * 32 + c], s);
        atomicMax(&pool_maxk[cur * 32 + c], f2key(mx));
        if (c == 0) atomicAdd(&pool_cnt[cur], (float)cnt);
      }
      cur = g; s = 0.f; mx = -INFINITY; cnt = 0;
    }
    s += v;
    mx = fmaxf(mx, v);
    cnt++;
  }
  if (cur >= 0) {
    atomicAdd(&pool_sum[cur * 32 + c], s);
    atomicMax(&pool_maxk[cur * 32 + c], f2key(mx));
    if (c == 0) atomicAdd(&pool_cnt[cur], (float)cnt);
  }
}

__global__ __launch_bounds__(256) void k_poolfinal(const float* __restrict__ pool_sum,
                                                   const unsigned* __restrict__ pool_maxk,
                                                   const float* __restrict__ pool_cnt,
                                                   const int* __restrict__ flg,
                                                   void* __restrict__ out) {
  bool ob = flg[3] != 0;
  int idx = blockIdx.x * 256 + threadIdx.x;
  if (idx >= NG * 64) return;
  int g = idx / 64, c = idx % 64;
  float cnt = pool_cnt[g];
  float val;
  if (c < 32) val = pool_sum[g * 32 + c] / fmaxf(cnt, 1.f);
  else val = cnt > 0.f ? key2f(pool_maxk[g * 32 + (c - 32)]) : 0.f;
  if (ob) ((u16*)out)[idx] = f2b(val);
  else ((float*)out)[idx] = val;
}

extern "C" void kernel_launch(void* const* d_in, const int* in_sizes, int n_in,
                              void* d_out, int out_size, void* d_ws, size_t ws_size,
                              hipStream_t stream) {
  (void)in_sizes; (void)n_in; (void)out_size; (void)ws_size;
  const void* x     = d_in[0];
  const int*  ei    = (const int*)d_in[1];
  const void* eattr = d_in[2];
  const int*  batch = (const int*)d_in[3];
  const void* skip1_W = d_in[4];
  const void* skip1_b = d_in[5];
  const void* c1_Wl = d_in[6];
  const void* c1_bl = d_in[7];
  const void* c1_Wr = d_in[8];
  const void* c1_br = d_in[9];
  const void* c1_We = d_in[10];
  const void* c1_att = d_in[11];
  const void* bn1_g = d_in[13];
  const void* bn1_b = d_in[14];
  const void* skip2_W = d_in[15];
  const void* skip2_b = d_in[16];
  const void* c2_Wl = d_in[17];
  const void* c2_bl = d_in[18];
  const void* c2_Wr = d_in[19];
  const void* c2_br = d_in[20];
  const void* c2_We = d_in[21];
  const void* c2_att = d_in[22];
  const void* bn2_g = d_in[24];
  const void* bn2_b = d_in[25];

  float* ws = (float*)d_ws;
  size_t off = 0;
  auto alloc = [&](size_t nfl) {
    float* p = ws + off;
    off += (nfl + 15) & ~(size_t)15;
    return p;
  };
  // ---- zero-initialized region (memset #1) ----
  int*   flags      = (int*)alloc(16);
  float* mean_sums  = alloc(16);
  int*   deg        = (int*)alloc(NN);
  float* bnsum1     = alloc(64);
  float* bnsq1      = alloc(64);
  float* bnsum2     = alloc(32);
  float* bnsq2      = alloc(32);
  float* pool_cnt   = alloc(NG);
  float* pool_sum   = alloc(NG * 32);
  unsigned* pool_maxk = (unsigned*)alloc(NG * 32);
  size_t zbytes = off * sizeof(float);
  // ---- plain scratch (fully written before read) ----
  int* start   = (int*)alloc(NN + 1);
  int* cursor  = (int*)alloc(NN);
  u16* csr_src = (u16*)alloc((size_t)ETOT / 2 + 8);   // ETOT u16
  unsigned* csr_lg = (unsigned*)alloc((size_t)ETOT);  // ETOT u32 (L1); L2 uses as u16
  u16* xl1 = (u16*)alloc((size_t)NN * 32);  // NN*64 bf16
  u16* xr1 = (u16*)alloc((size_t)NN * 32);  // NN*64 bf16; h1 overlays after edgeA1
  u16* hp1 = (u16*)alloc((size_t)NN * 32);  // NN*64 bf16; hp2/h2 overlay halves
  u16* agg = (u16*)alloc((size_t)NN * 32);  // NN*64 bf16 (L1); L2 uses first half
  // layer-2 overlays (source regions dead by then)
  u16* h1  = xr1;
  u16* xl2 = xl1;
  u16* xr2 = xl1 + (size_t)NN * 32;
  u16* hp2 = hp1;
  u16* h2  = hp1 + (size_t)NN * 32;

  hipMemsetAsync(d_ws, 0, zbytes, stream);
  k_detect<<<1, 256, 0, stream>>>((const unsigned*)x, (const unsigned*)skip1_W,
                                  (const unsigned*)eattr, flags);
  k_ea_colsum<<<128, 256, 0, stream>>>(eattr, flags, mean_sums);

  // CSR build (graph identical for both layers)
  int eg = (ETOT + 255) / 256;
  k_hist<<<eg, 256, 0, stream>>>(ei, deg);
  k_scan<<<1, 256, 0, stream>>>(deg, start);

  // ---- layer 1 ----
  {
    dim3 g((NN + 31) / 32, 3);
    k_linear3<128, 64, 0><<<g, 256, 0, stream>>>(x, flags, c1_Wl, c1_Wr, skip1_W,
                                                 c1_bl, c1_br, skip1_b,
                                                 xl1, xr1, hp1, NN);
  }
  k_copy<<<(NN + 255) / 256, 256, 0, stream>>>(start, cursor, NN);
  k_edgeA<2, 32><<<eg, 256, 0, stream>>>(ei, eattr, flags, mean_sums, xl1, xr1,
                                         c1_We, c1_att, cursor, csr_src, csr_lg);
  k_reduce<2, 32><<<(NN * 64 + 255) / 256, 256, 0, stream>>>(start, csr_src, csr_lg,
                                                             xl1, agg);
  k_bnred<64><<<256, 256, 0, stream>>>(agg, bnsum1, bnsq1, NN);
  k_bnapply<64><<<(NN * 64 + 255) / 256, 256, 0, stream>>>(agg, hp1, bnsum1, bnsq1,
                                                           bn1_g, bn1_b, flags, h1, NN);

  // ---- layer 2 ----
  {
    dim3 g((NN + 31) / 32, 3);
    k_linear3<64, 32, 1><<<g, 256, 0, stream>>>(h1, flags, c2_Wl, c2_Wr, skip2_W,
                                                c2_bl, c2_br, skip2_b,
                                                xl2, xr2, hp2, NN);
  }
  k_copy<<<(NN + 255) / 256, 256, 0, stream>>>(start, cursor, NN);
  k_edgeA<1, 32><<<eg, 256, 0, stream>>>(ei, eattr, flags, mean_sums, xl2, xr2,
                                         c2_We, c2_att, cursor, csr_src, csr_lg);
  k_reduce<1, 32><<<(NN * 32 + 255) / 256, 256, 0, stream>>>(start, csr_src, csr_lg,
                                                             xl2, agg);
  k_bnred<32><<<256, 256, 0, stream>>>(agg, bnsum2, bnsq2, NN);
  k_bnapply<32><<<(NN * 32 + 255) / 256, 256, 0, stream>>>(agg, hp2, bnsum2, bnsq2,
                                                           bn2_g, bn2_b, flags, h2, NN);

  k_pool<<<(NN + 2047) / 2048, 256, 0, stream>>>(h2, batch, pool_sum, pool_maxk, pool_cnt, NN);
  k_poolfinal<<<4, 256, 0, stream>>>(pool_sum, pool_maxk, pool_cnt, flags, d_out);
}